// Round 1
// baseline (792.261 us; speedup 1.0000x reference)
//
#include <hip/hip_runtime.h>

#define NFEAT 64
#define BSHIFT 8
#define BCOLS 256              // cols/rows per bucket = 1<<BSHIFT
#define NBMAX 512              // array size >= nbuck = ceil(100000/256) = 391
#define CAP 5120               // per-bucket capacity (mean 4092 + 16 sigma)
#define CHUNK 4096             // edges per partition block
#define PT 512                 // partition threads
#define NITP (CHUNK / PT)      // 8 reg-cached entries per thread
#define FT 512                 // fill threads
#define GT 512                 // gather threads (8 waves)

// ---------------------------------------------------------------------------
// out[c,f] = dinv[c]^2 x[c,f] + dinv[c] * sum_{e: col==c} dinv[row_e] x[row_e,f]
// dinv[i] = rsqrt(1 + deg_row[i])
//
// NO random global atomics (r10: 1.6M random atomics = 66us, 41ns each).
//   k_init   : bump cursors bcur/bcurR = b*CAP
//   k_partCR : fused dual partition from one edge read:
//                part[]  int   (col&255)<<17|row  by col-bucket
//                partR[] uchar row&255            by row-bucket (-> degrees)
//   k_fillR  : per bucket: count partR -> dinv + xs=bf16(dinv*x)
//   k_gather2: block per bucket; 256x64 f32 out-tile in LDS (64KB);
//              per edge: 8 lanes x 16B bf16 row -> 8 ds_add_f32 each,
//              XOR-swizzled (k ^ (col&7)) to spread banks across the 8
//              concurrent edge-groups. NO per-col sort, NO csr rewrite,
//              NO per-node shfl reduction.
// ---------------------------------------------------------------------------

__device__ __forceinline__ unsigned short f2bf(float f) {
    unsigned int u = __float_as_uint(f);
    return (unsigned short)((u + 0x7FFFu + ((u >> 16) & 1u)) >> 16);  // RNE
}

__device__ __forceinline__ float bflo(unsigned int u) {
    return __uint_as_float(u << 16);
}
__device__ __forceinline__ float bfhi(unsigned int u) {
    return __uint_as_float(u & 0xFFFF0000u);
}

__device__ __forceinline__ int wave_incl_scan(int v, int lane) {
    #pragma unroll
    for (int off = 1; off < 64; off <<= 1) {
        int u = __shfl_up(v, off);
        if (lane >= off) v += u;
    }
    return v;
}

__global__ void k_init(int* __restrict__ bcur, int* __restrict__ bcurR) {
    int t = threadIdx.x;           // NBMAX
    bcur[t]  = t * CAP;
    bcurR[t] = t * CAP;
}

// fused dual partition: col-buckets (int entries) + row-buckets (uchar)
__global__ __launch_bounds__(PT)
void k_partCR(const int* __restrict__ rows, const int* __restrict__ cols,
              int* __restrict__ bcur, int* __restrict__ bcurR,
              int* __restrict__ part, unsigned char* __restrict__ partR, int E) {
    __shared__ int histC[NBMAX];
    __shared__ int histR[NBMAX];
    __shared__ int gbaseC[NBMAX];
    __shared__ int gbaseR[NBMAX];
    __shared__ int wsumC[8];
    __shared__ int wsumR[8];
    __shared__ int stageC[CHUNK];
    __shared__ unsigned char stageR[CHUNK];
    __shared__ unsigned short bidC[CHUNK];
    __shared__ unsigned short bidR[CHUNK];
    int chunk0 = blockIdx.x * CHUNK;
    int cnt = min(CHUNK, E - chunk0);
    int t = threadIdx.x;           // PT = 512
    int lane = t & 63, wid = t >> 6;

    histC[t] = 0; histR[t] = 0;
    __syncthreads();

    int pk[NITP];
    unsigned char rpk[NITP];
    unsigned short cb[NITP], rb[NITP];
    #pragma unroll
    for (int k = 0; k < NITP; k++) {
        int i = t + k * PT;
        if (i < cnt) {
            int c = cols[chunk0 + i];
            int r = rows[chunk0 + i];
            int b  = c >> BSHIFT;
            int b2 = r >> BSHIFT;
            pk[k]  = ((c & (BCOLS - 1)) << 17) | r;
            rpk[k] = (unsigned char)(r & (BCOLS - 1));
            cb[k] = (unsigned short)b;
            rb[k] = (unsigned short)b2;
            atomicAdd(&histC[b], 1);
            atomicAdd(&histR[b2], 1);
        }
    }
    __syncthreads();

    // two 512-bin scans (all 8 waves each), separate wsum arrays, one barrier
    int v1 = histC[t];
    int inc1 = wave_incl_scan(v1, lane);
    if (lane == 63) wsumC[wid] = inc1;
    int v2 = histR[t];
    int inc2 = wave_incl_scan(v2, lane);
    if (lane == 63) wsumR[wid] = inc2;
    __syncthreads();
    int addC = 0, addR = 0;
    #pragma unroll
    for (int k = 0; k < 8; k++) {
        if (k < wid) { addC += wsumC[k]; addR += wsumR[k]; }
    }
    int exC = inc1 - v1 + addC;
    int exR = inc2 - v2 + addR;
    gbaseC[t] = (v1 > 0) ? (atomicAdd(&bcur[t], v1) - exC) : 0;
    gbaseR[t] = (v2 > 0) ? (atomicAdd(&bcurR[t], v2) - exR) : 0;
    histC[t] = exC;                // becomes cursor
    histR[t] = exR;
    __syncthreads();

    #pragma unroll
    for (int k = 0; k < NITP; k++) {
        int i = t + k * PT;
        if (i < cnt) {
            int p = atomicAdd(&histC[cb[k]], 1);
            stageC[p] = pk[k];
            bidC[p] = cb[k];
            int p2 = atomicAdd(&histR[rb[k]], 1);
            stageR[p2] = rpk[k];
            bidR[p2] = rb[k];
        }
    }
    __syncthreads();
    for (int p = t; p < cnt; p += PT) {
        int b = bidC[p];
        int idx = gbaseC[b] + p;
        if (idx < (b + 1) * CAP) part[idx] = stageC[p];      // overflow clamp
        int b2 = bidR[p];
        int idx2 = gbaseR[b2] + p;
        if (idx2 < (b2 + 1) * CAP) partR[idx2] = stageR[p];
    }
}

// per bucket: row counts -> dinv + xs = bf16(dinv*x)
__global__ __launch_bounds__(FT)
void k_fillR(const unsigned char* __restrict__ partR, const int* __restrict__ bcurR,
             const float4* __restrict__ x4, float* __restrict__ dinv,
             ushort4* __restrict__ xs4, int n) {
    __shared__ int lcnt[BCOLS];
    __shared__ float ldinv[BCOLS];
    int b = blockIdx.x;
    int s = b * CAP;
    int t = threadIdx.x;           // FT = 512

    int cntR = min(bcurR[b] - s, CAP);
    if (t < BCOLS) lcnt[t] = 0;
    __syncthreads();
    for (int i = t; i < cntR; i += FT)
        atomicAdd(&lcnt[partR[s + i]], 1);
    __syncthreads();
    if (t < BCOLS) {
        float d = rsqrtf((float)(lcnt[t] + 1));      // +1 self loop
        ldinv[t] = d;
        int gr = (b << BSHIFT) + t;
        if (gr < n) dinv[gr] = d;
    }
    __syncthreads();
    size_t base4 = (size_t)(b << BSHIFT) << 4;       // float4 index of row b*256
    int lim = min(BCOLS, n - (b << BSHIFT)) << 4;
    for (int i = t; i < lim; i += FT) {
        float dd = ldinv[i >> 4];
        float4 vv = x4[base4 + i];
        ushort4 o;
        o.x = f2bf(dd * vv.x); o.y = f2bf(dd * vv.y);
        o.z = f2bf(dd * vv.z); o.w = f2bf(dd * vv.w);
        xs4[base4 + i] = o;
    }
}

// block per bucket: accumulate all bucket edges into a 256x64 f32 LDS tile.
// wave handles 16 edges/iter (2 rounds of 8 groups x 8 lanes x 16B xs row).
// LDS slot (c, f=li*8+k) -> acc[c*64 + li*8 + (k ^ (c&7))]:
//   bank = (li&3)*8 + (k^(c&7)) -> per-group 2-way (free), cross-group
//   collisions only when cols match mod 8.
__global__ __launch_bounds__(GT)
void k_gather2(const int* __restrict__ part, const int* __restrict__ bcur,
               const unsigned short* __restrict__ xs,
               const float* __restrict__ dinv,
               float4* __restrict__ out4, int n) {
    __shared__ __align__(16) float acc[BCOLS * NFEAT];   // 64 KB
    int b = blockIdx.x;
    int s = b * CAP;
    int cnt = min(bcur[b] - s, CAP);
    int t = threadIdx.x;           // GT = 512
    int lane = t & 63, wid = t >> 6;
    int g = lane >> 3, li = lane & 7;

    float4* acc4 = (float4*)acc;
    for (int i = t; i < BCOLS * NFEAT / 4; i += GT)
        acc4[i] = make_float4(0.f, 0.f, 0.f, 0.f);
    __syncthreads();

    for (int base = wid * 16; base < cnt; base += GT / 64 * 16) {
        int i0 = base + li;
        int i1 = base + 8 + li;
        int e0 = (i0 < cnt) ? part[s + i0] : 0;
        int e1 = (i1 < cnt) ? part[s + i1] : 0;
        int mA = __shfl(e0, g);            // entry of edge base+g
        int mB = __shfl(e1, g);            // entry of edge base+8+g
        bool vA = (base + g) < cnt;
        bool vB = (base + 8 + g) < cnt;
        int rA = mA & 0x1FFFF, cA = (mA >> 17) & (BCOLS - 1);
        int rB = mB & 0x1FFFF, cB = (mB >> 17) & (BCOLS - 1);
        uint4 uA = *((const uint4*)(xs + ((size_t)rA << 6)) + li);
        uint4 uB = *((const uint4*)(xs + ((size_t)rB << 6)) + li);
        if (vA) {
            int ba = cA * NFEAT + li * 8;
            int sw = cA & 7;
            atomicAdd(&acc[ba + (0 ^ sw)], bflo(uA.x));
            atomicAdd(&acc[ba + (1 ^ sw)], bfhi(uA.x));
            atomicAdd(&acc[ba + (2 ^ sw)], bflo(uA.y));
            atomicAdd(&acc[ba + (3 ^ sw)], bfhi(uA.y));
            atomicAdd(&acc[ba + (4 ^ sw)], bflo(uA.z));
            atomicAdd(&acc[ba + (5 ^ sw)], bfhi(uA.z));
            atomicAdd(&acc[ba + (6 ^ sw)], bflo(uA.w));
            atomicAdd(&acc[ba + (7 ^ sw)], bfhi(uA.w));
        }
        if (vB) {
            int ba = cB * NFEAT + li * 8;
            int sw = cB & 7;
            atomicAdd(&acc[ba + (0 ^ sw)], bflo(uB.x));
            atomicAdd(&acc[ba + (1 ^ sw)], bfhi(uB.x));
            atomicAdd(&acc[ba + (2 ^ sw)], bflo(uB.y));
            atomicAdd(&acc[ba + (3 ^ sw)], bfhi(uB.y));
            atomicAdd(&acc[ba + (4 ^ sw)], bflo(uB.z));
            atomicAdd(&acc[ba + (5 ^ sw)], bfhi(uB.z));
            atomicAdd(&acc[ba + (6 ^ sw)], bflo(uB.w));
            atomicAdd(&acc[ba + (7 ^ sw)], bfhi(uB.w));
        }
    }
    __syncthreads();

    // epilogue: out[node] = dinv[node] * (acc[node] + xs[node])
    for (int i = t; i < BCOLS * 8; i += GT) {
        int c = i >> 3, l2 = i & 7;
        int node = (b << BSHIFT) + c;
        if (node < n) {
            float dc = dinv[node];
            uint4 us = *((const uint4*)(xs + ((size_t)node << 6)) + l2);
            int ba = c * NFEAT + l2 * 8;
            int sw = c & 7;
            float4 r0, r1;
            r0.x = dc * (acc[ba + (0 ^ sw)] + bflo(us.x));
            r0.y = dc * (acc[ba + (1 ^ sw)] + bfhi(us.x));
            r0.z = dc * (acc[ba + (2 ^ sw)] + bflo(us.y));
            r0.w = dc * (acc[ba + (3 ^ sw)] + bfhi(us.y));
            r1.x = dc * (acc[ba + (4 ^ sw)] + bflo(us.z));
            r1.y = dc * (acc[ba + (5 ^ sw)] + bfhi(us.z));
            r1.z = dc * (acc[ba + (6 ^ sw)] + bflo(us.w));
            r1.w = dc * (acc[ba + (7 ^ sw)] + bfhi(us.w));
            size_t ob = ((size_t)node << 4) + (l2 << 1);
            out4[ob] = r0;
            out4[ob + 1] = r1;
        }
    }
}

extern "C" void kernel_launch(void* const* d_in, const int* in_sizes, int n_in,
                              void* d_out, int out_size, void* d_ws, size_t ws_size,
                              hipStream_t stream) {
    const float* x    = (const float*)d_in[0];
    const int*   eidx = (const int*)d_in[1];   // int32 (JAX x64 disabled)

    const int n = in_sizes[0] / NFEAT;         // 100000
    const int E = in_sizes[1] / 2;             // 1600000
    const int* rows = eidx;
    const int* cols = eidx + E;
    float* out = (float*)d_out;

    const int nbuck = (n + BCOLS - 1) >> BSHIFT;   // 391

    // ws: bcur[NBMAX] | bcurR[NBMAX] | dinv[n]
    //     | xs[n*64 bf16, 16B-aligned] | part[nbuck*CAP ints] | partR[uchar]
    char* w = (char*)d_ws;
    int*   bcur  = (int*)w;     w += NBMAX * 4;
    int*   bcurR = (int*)w;     w += NBMAX * 4;
    float* dinv  = (float*)w;   w += (size_t)n * 4;
    w = (char*)(((uintptr_t)w + 15) & ~(uintptr_t)15);
    unsigned short* xs = (unsigned short*)w;  w += (size_t)n * NFEAT * 2;
    int*   part  = (int*)w;     w += (size_t)nbuck * CAP * 4;
    unsigned char* partR = (unsigned char*)w;

    k_init<<<1, NBMAX, 0, stream>>>(bcur, bcurR);

    int nchunk = (E + CHUNK - 1) / CHUNK;      // 391
    k_partCR<<<nchunk, PT, 0, stream>>>(rows, cols, bcur, bcurR, part, partR, E);
    k_fillR<<<nbuck, FT, 0, stream>>>(partR, bcurR, (const float4*)x,
                                      dinv, (ushort4*)xs, n);
    k_gather2<<<nbuck, GT, 0, stream>>>(part, bcur, xs, dinv,
                                        (float4*)out, n);
}

// Round 2
// 788.728 us; speedup vs baseline: 1.0045x; 1.0045x over previous
//
#include <hip/hip_runtime.h>

#define NFEAT 64
#define BSHIFT 8
#define BCOLS 256              // cols/rows per bucket = 1<<BSHIFT
#define NBMAX 512              // array size >= nbuck = ceil(100000/256) = 391
#define CAP 5120               // per-bucket capacity (mean 4092 + 16 sigma)
#define CHUNK 4096             // edges per partition block
#define PT 512                 // partition threads
#define NITP (CHUNK / PT)      // 8 reg-cached entries per thread
#define FT 512                 // fill threads
#define GT 512                 // gather threads (8 waves)

// ---------------------------------------------------------------------------
// out[c,f] = dinv[c]^2 x[c,f] + dinv[c] * sum_{e: col==c} dinv[row_e] x[row_e,f]
// dinv[i] = rsqrt(1 + deg_row[i])
//
//   k_init   : bump cursors bcur/bcurR = b*CAP
//   k_partCR : fused dual partition from one edge read:
//                part[]  int   (col&255)<<17|row  by col-bucket
//                partR[] uchar row&255            by row-bucket (-> degrees)
//   k_fillR  : per bucket: count partR -> dinv + xs=bf16(dinv*x)
//   k_gather2: block per bucket; 256x64 f32 out-tile in LDS (64KB);
//              per edge: 8 lanes x 16B bf16 row -> 8 NATIVE ds_add_f32 each
//              (inline asm; HIP atomicAdd on shared float = CAS loop, 100x
//              slower — r1: 690us, VALUBusy 1.9%). XOR-swizzle (k ^ (col&7))
//              spreads banks across the 8 concurrent edge-groups -> 2-way
//              per group (free), no same-address serialization except
//              duplicate cols.
// ---------------------------------------------------------------------------

__device__ __forceinline__ unsigned short f2bf(float f) {
    unsigned int u = __float_as_uint(f);
    return (unsigned short)((u + 0x7FFFu + ((u >> 16) & 1u)) >> 16);  // RNE
}

__device__ __forceinline__ float bflo(unsigned int u) {
    return __uint_as_float(u << 16);
}
__device__ __forceinline__ float bfhi(unsigned int u) {
    return __uint_as_float(u & 0xFFFF0000u);
}

// native LDS float atomic add, fire-and-forget (no return, no CAS loop).
// addr = byte offset into LDS (low 32 bits of generic pointer to __shared__).
__device__ __forceinline__ void lds_fadd(unsigned addr, float v) {
    asm volatile("ds_add_f32 %0, %1" :: "v"(addr), "v"(v));
}

__device__ __forceinline__ int wave_incl_scan(int v, int lane) {
    #pragma unroll
    for (int off = 1; off < 64; off <<= 1) {
        int u = __shfl_up(v, off);
        if (lane >= off) v += u;
    }
    return v;
}

__global__ void k_init(int* __restrict__ bcur, int* __restrict__ bcurR) {
    int t = threadIdx.x;           // NBMAX
    bcur[t]  = t * CAP;
    bcurR[t] = t * CAP;
}

// fused dual partition: col-buckets (int entries) + row-buckets (uchar)
__global__ __launch_bounds__(PT)
void k_partCR(const int* __restrict__ rows, const int* __restrict__ cols,
              int* __restrict__ bcur, int* __restrict__ bcurR,
              int* __restrict__ part, unsigned char* __restrict__ partR, int E) {
    __shared__ int histC[NBMAX];
    __shared__ int histR[NBMAX];
    __shared__ int gbaseC[NBMAX];
    __shared__ int gbaseR[NBMAX];
    __shared__ int wsumC[8];
    __shared__ int wsumR[8];
    __shared__ int stageC[CHUNK];
    __shared__ unsigned char stageR[CHUNK];
    __shared__ unsigned short bidC[CHUNK];
    __shared__ unsigned short bidR[CHUNK];
    int chunk0 = blockIdx.x * CHUNK;
    int cnt = min(CHUNK, E - chunk0);
    int t = threadIdx.x;           // PT = 512
    int lane = t & 63, wid = t >> 6;

    histC[t] = 0; histR[t] = 0;
    __syncthreads();

    int pk[NITP];
    unsigned char rpk[NITP];
    unsigned short cb[NITP], rb[NITP];
    #pragma unroll
    for (int k = 0; k < NITP; k++) {
        int i = t + k * PT;
        if (i < cnt) {
            int c = cols[chunk0 + i];
            int r = rows[chunk0 + i];
            int b  = c >> BSHIFT;
            int b2 = r >> BSHIFT;
            pk[k]  = ((c & (BCOLS - 1)) << 17) | r;
            rpk[k] = (unsigned char)(r & (BCOLS - 1));
            cb[k] = (unsigned short)b;
            rb[k] = (unsigned short)b2;
            atomicAdd(&histC[b], 1);
            atomicAdd(&histR[b2], 1);
        }
    }
    __syncthreads();

    // two 512-bin scans (all 8 waves each), separate wsum arrays, one barrier
    int v1 = histC[t];
    int inc1 = wave_incl_scan(v1, lane);
    if (lane == 63) wsumC[wid] = inc1;
    int v2 = histR[t];
    int inc2 = wave_incl_scan(v2, lane);
    if (lane == 63) wsumR[wid] = inc2;
    __syncthreads();
    int addC = 0, addR = 0;
    #pragma unroll
    for (int k = 0; k < 8; k++) {
        if (k < wid) { addC += wsumC[k]; addR += wsumR[k]; }
    }
    int exC = inc1 - v1 + addC;
    int exR = inc2 - v2 + addR;
    gbaseC[t] = (v1 > 0) ? (atomicAdd(&bcur[t], v1) - exC) : 0;
    gbaseR[t] = (v2 > 0) ? (atomicAdd(&bcurR[t], v2) - exR) : 0;
    histC[t] = exC;                // becomes cursor
    histR[t] = exR;
    __syncthreads();

    #pragma unroll
    for (int k = 0; k < NITP; k++) {
        int i = t + k * PT;
        if (i < cnt) {
            int p = atomicAdd(&histC[cb[k]], 1);
            stageC[p] = pk[k];
            bidC[p] = cb[k];
            int p2 = atomicAdd(&histR[rb[k]], 1);
            stageR[p2] = rpk[k];
            bidR[p2] = rb[k];
        }
    }
    __syncthreads();
    for (int p = t; p < cnt; p += PT) {
        int b = bidC[p];
        int idx = gbaseC[b] + p;
        if (idx < (b + 1) * CAP) part[idx] = stageC[p];      // overflow clamp
        int b2 = bidR[p];
        int idx2 = gbaseR[b2] + p;
        if (idx2 < (b2 + 1) * CAP) partR[idx2] = stageR[p];
    }
}

// per bucket: row counts -> dinv + xs = bf16(dinv*x)
__global__ __launch_bounds__(FT)
void k_fillR(const unsigned char* __restrict__ partR, const int* __restrict__ bcurR,
             const float4* __restrict__ x4, float* __restrict__ dinv,
             ushort4* __restrict__ xs4, int n) {
    __shared__ int lcnt[BCOLS];
    __shared__ float ldinv[BCOLS];
    int b = blockIdx.x;
    int s = b * CAP;
    int t = threadIdx.x;           // FT = 512

    int cntR = min(bcurR[b] - s, CAP);
    if (t < BCOLS) lcnt[t] = 0;
    __syncthreads();
    for (int i = t; i < cntR; i += FT)
        atomicAdd(&lcnt[partR[s + i]], 1);
    __syncthreads();
    if (t < BCOLS) {
        float d = rsqrtf((float)(lcnt[t] + 1));      // +1 self loop
        ldinv[t] = d;
        int gr = (b << BSHIFT) + t;
        if (gr < n) dinv[gr] = d;
    }
    __syncthreads();
    size_t base4 = (size_t)(b << BSHIFT) << 4;       // float4 index of row b*256
    int lim = min(BCOLS, n - (b << BSHIFT)) << 4;
    for (int i = t; i < lim; i += FT) {
        float dd = ldinv[i >> 4];
        float4 vv = x4[base4 + i];
        ushort4 o;
        o.x = f2bf(dd * vv.x); o.y = f2bf(dd * vv.y);
        o.z = f2bf(dd * vv.z); o.w = f2bf(dd * vv.w);
        xs4[base4 + i] = o;
    }
}

// block per bucket: accumulate all bucket edges into a 256x64 f32 LDS tile.
// wave handles 16 edges/iter (2 rounds of 8 groups x 8 lanes x 16B xs row).
// LDS slot (c, f=li*8+k) -> acc[c*64 + li*8 + (k ^ (c&7))]:
//   bank = (li&3)*8 + (k^(c&7)) -> per-group 2-way (free), cross-group
//   collisions only when cols match mod 8.
// Per-edge addr: aX = base(c,li) ^ ((c&7)<<2); slot k addr = aX ^ (k<<2)
//   (legal bitwise: base is 32B-aligned, k<<2 < 32).
__global__ __launch_bounds__(GT)
void k_gather2(const int* __restrict__ part, const int* __restrict__ bcur,
               const unsigned short* __restrict__ xs,
               const float* __restrict__ dinv,
               float4* __restrict__ out4, int n) {
    __shared__ __align__(64) float acc[BCOLS * NFEAT];   // 64 KB
    int b = blockIdx.x;
    int s = b * CAP;
    int cnt = min(bcur[b] - s, CAP);
    int t = threadIdx.x;           // GT = 512
    int lane = t & 63, wid = t >> 6;
    int g = lane >> 3, li = lane & 7;

    float4* acc4 = (float4*)acc;
    for (int i = t; i < BCOLS * NFEAT / 4; i += GT)
        acc4[i] = make_float4(0.f, 0.f, 0.f, 0.f);
    __syncthreads();

    unsigned accBase = (unsigned)(size_t)acc;   // LDS byte offset of acc[0]
    unsigned liOff = (unsigned)(li * 8) << 2;

    for (int base = wid * 16; base < cnt; base += GT / 64 * 16) {
        int i0 = base + li;
        int i1 = base + 8 + li;
        int e0 = (i0 < cnt) ? part[s + i0] : 0;
        int e1 = (i1 < cnt) ? part[s + i1] : 0;
        int mA = __shfl(e0, g);            // entry of edge base+g
        int mB = __shfl(e1, g);            // entry of edge base+8+g
        bool vA = (base + g) < cnt;
        bool vB = (base + 8 + g) < cnt;
        int rA = mA & 0x1FFFF, cA = (mA >> 17) & (BCOLS - 1);
        int rB = mB & 0x1FFFF, cB = (mB >> 17) & (BCOLS - 1);
        uint4 uA = *((const uint4*)(xs + ((size_t)rA << 6)) + li);
        uint4 uB = *((const uint4*)(xs + ((size_t)rB << 6)) + li);
        if (vA) {
            unsigned aX = (accBase + (((unsigned)cA * NFEAT) << 2) + liOff)
                          ^ (((unsigned)cA & 7u) << 2);
            lds_fadd(aX,            bflo(uA.x));
            lds_fadd(aX ^ (1u<<2),  bfhi(uA.x));
            lds_fadd(aX ^ (2u<<2),  bflo(uA.y));
            lds_fadd(aX ^ (3u<<2),  bfhi(uA.y));
            lds_fadd(aX ^ (4u<<2),  bflo(uA.z));
            lds_fadd(aX ^ (5u<<2),  bfhi(uA.z));
            lds_fadd(aX ^ (6u<<2),  bflo(uA.w));
            lds_fadd(aX ^ (7u<<2),  bfhi(uA.w));
        }
        if (vB) {
            unsigned aX = (accBase + (((unsigned)cB * NFEAT) << 2) + liOff)
                          ^ (((unsigned)cB & 7u) << 2);
            lds_fadd(aX,            bflo(uB.x));
            lds_fadd(aX ^ (1u<<2),  bfhi(uB.x));
            lds_fadd(aX ^ (2u<<2),  bflo(uB.y));
            lds_fadd(aX ^ (3u<<2),  bfhi(uB.y));
            lds_fadd(aX ^ (4u<<2),  bflo(uB.z));
            lds_fadd(aX ^ (5u<<2),  bfhi(uB.z));
            lds_fadd(aX ^ (6u<<2),  bflo(uB.w));
            lds_fadd(aX ^ (7u<<2),  bfhi(uB.w));
        }
    }
    __syncthreads();   // lgkmcnt(0) drain covers the asm ds_adds (hw counter)

    // epilogue: out[node] = dinv[node] * (acc[node] + xs[node])
    for (int i = t; i < BCOLS * 8; i += GT) {
        int c = i >> 3, l2 = i & 7;
        int node = (b << BSHIFT) + c;
        if (node < n) {
            float dc = dinv[node];
            uint4 us = *((const uint4*)(xs + ((size_t)node << 6)) + l2);
            int ba = c * NFEAT + l2 * 8;
            int sw = c & 7;
            float4 r0, r1;
            r0.x = dc * (acc[ba + (0 ^ sw)] + bflo(us.x));
            r0.y = dc * (acc[ba + (1 ^ sw)] + bfhi(us.x));
            r0.z = dc * (acc[ba + (2 ^ sw)] + bflo(us.y));
            r0.w = dc * (acc[ba + (3 ^ sw)] + bfhi(us.y));
            r1.x = dc * (acc[ba + (4 ^ sw)] + bflo(us.z));
            r1.y = dc * (acc[ba + (5 ^ sw)] + bfhi(us.z));
            r1.z = dc * (acc[ba + (6 ^ sw)] + bflo(us.w));
            r1.w = dc * (acc[ba + (7 ^ sw)] + bfhi(us.w));
            size_t ob = ((size_t)node << 4) + (l2 << 1);
            out4[ob] = r0;
            out4[ob + 1] = r1;
        }
    }
}

extern "C" void kernel_launch(void* const* d_in, const int* in_sizes, int n_in,
                              void* d_out, int out_size, void* d_ws, size_t ws_size,
                              hipStream_t stream) {
    const float* x    = (const float*)d_in[0];
    const int*   eidx = (const int*)d_in[1];   // int32 (JAX x64 disabled)

    const int n = in_sizes[0] / NFEAT;         // 100000
    const int E = in_sizes[1] / 2;             // 1600000
    const int* rows = eidx;
    const int* cols = eidx + E;
    float* out = (float*)d_out;

    const int nbuck = (n + BCOLS - 1) >> BSHIFT;   // 391

    // ws: bcur[NBMAX] | bcurR[NBMAX] | dinv[n]
    //     | xs[n*64 bf16, 16B-aligned] | part[nbuck*CAP ints] | partR[uchar]
    char* w = (char*)d_ws;
    int*   bcur  = (int*)w;     w += NBMAX * 4;
    int*   bcurR = (int*)w;     w += NBMAX * 4;
    float* dinv  = (float*)w;   w += (size_t)n * 4;
    w = (char*)(((uintptr_t)w + 15) & ~(uintptr_t)15);
    unsigned short* xs = (unsigned short*)w;  w += (size_t)n * NFEAT * 2;
    int*   part  = (int*)w;     w += (size_t)nbuck * CAP * 4;
    unsigned char* partR = (unsigned char*)w;

    k_init<<<1, NBMAX, 0, stream>>>(bcur, bcurR);

    int nchunk = (E + CHUNK - 1) / CHUNK;      // 391
    k_partCR<<<nchunk, PT, 0, stream>>>(rows, cols, bcur, bcurR, part, partR, E);
    k_fillR<<<nbuck, FT, 0, stream>>>(partR, bcurR, (const float4*)x,
                                      dinv, (ushort4*)xs, n);
    k_gather2<<<nbuck, GT, 0, stream>>>(part, bcur, xs, dinv,
                                        (float4*)out, n);
}

// Round 3
// 140.482 us; speedup vs baseline: 5.6396x; 5.6145x over previous
//
#include <hip/hip_runtime.h>

#define NFEAT 64
#define BSHIFT 8
#define BCOLS 256              // cols/rows per bucket = 1<<BSHIFT
#define NBMAX 512              // array size >= nbuck = ceil(100000/256) = 391
#define CAP 5120               // per-bucket capacity (mean 4092 + 16 sigma)
#define CHUNK 4096             // edges per partition block
#define PT 512                 // partition threads
#define NITP (CHUNK / PT)      // 8 reg-cached entries per thread
#define FT 512                 // fill threads
#define UT 512                 // fuse threads (8 waves)
#define FBIT (CAP / UT)        // 10 reg-cached entries per fuse thread

// ---------------------------------------------------------------------------
// out[c,f] = dinv[c]^2 x[c,f] + dinv[c] * sum_{e: col==c} dinv[row_e] x[row_e,f]
// dinv[i] = rsqrt(1 + deg_row[i])
//
//   k_init   : bump cursors bcur/bcurR = b*CAP
//   k_partCR : fused dual partition from one edge read:
//                part[]  int   (col&255)<<17|row  by col-bucket
//                partR[] uchar row&255            by row-bucket (-> degrees)
//   k_fillR  : per bucket: count partR -> dinv + xs=bf16(dinv*x)
//   k_fuse   : per bucket: build per-col CSR in LDS (count/scan/scatter,
//              native int LDS atomics), then gather in the same block:
//              64 groups x 8 lanes, group owns 4 cols serially; per edge
//              read stage[p] (LDS broadcast) + 128B xs row, accumulate in
//              registers. No shfl broadcast/masks/reduce epilogue; no
//              global CSR/ptr round-trip.
//
// r1/r2 lesson: LDS f32 atomics (ds_add_f32) retire ~4 cyc/lane-add
// regardless of banking -> 690us for 102M adds. Dead end; CSR+registers it is.
// ---------------------------------------------------------------------------

__device__ __forceinline__ unsigned short f2bf(float f) {
    unsigned int u = __float_as_uint(f);
    return (unsigned short)((u + 0x7FFFu + ((u >> 16) & 1u)) >> 16);  // RNE
}

__device__ __forceinline__ float bflo(unsigned int u) {
    return __uint_as_float(u << 16);
}
__device__ __forceinline__ float bfhi(unsigned int u) {
    return __uint_as_float(u & 0xFFFF0000u);
}

__device__ __forceinline__ int wave_incl_scan(int v, int lane) {
    #pragma unroll
    for (int off = 1; off < 64; off <<= 1) {
        int u = __shfl_up(v, off);
        if (lane >= off) v += u;
    }
    return v;
}

__global__ void k_init(int* __restrict__ bcur, int* __restrict__ bcurR) {
    int t = threadIdx.x;           // NBMAX
    bcur[t]  = t * CAP;
    bcurR[t] = t * CAP;
}

// fused dual partition: col-buckets (int entries) + row-buckets (uchar)
__global__ __launch_bounds__(PT)
void k_partCR(const int* __restrict__ rows, const int* __restrict__ cols,
              int* __restrict__ bcur, int* __restrict__ bcurR,
              int* __restrict__ part, unsigned char* __restrict__ partR, int E) {
    __shared__ int histC[NBMAX];
    __shared__ int histR[NBMAX];
    __shared__ int gbaseC[NBMAX];
    __shared__ int gbaseR[NBMAX];
    __shared__ int wsumC[8];
    __shared__ int wsumR[8];
    __shared__ int stageC[CHUNK];
    __shared__ unsigned char stageR[CHUNK];
    __shared__ unsigned short bidC[CHUNK];
    __shared__ unsigned short bidR[CHUNK];
    int chunk0 = blockIdx.x * CHUNK;
    int cnt = min(CHUNK, E - chunk0);
    int t = threadIdx.x;           // PT = 512
    int lane = t & 63, wid = t >> 6;

    histC[t] = 0; histR[t] = 0;
    __syncthreads();

    int pk[NITP];
    unsigned char rpk[NITP];
    unsigned short cb[NITP], rb[NITP];
    #pragma unroll
    for (int k = 0; k < NITP; k++) {
        int i = t + k * PT;
        if (i < cnt) {
            int c = cols[chunk0 + i];
            int r = rows[chunk0 + i];
            int b  = c >> BSHIFT;
            int b2 = r >> BSHIFT;
            pk[k]  = ((c & (BCOLS - 1)) << 17) | r;
            rpk[k] = (unsigned char)(r & (BCOLS - 1));
            cb[k] = (unsigned short)b;
            rb[k] = (unsigned short)b2;
            atomicAdd(&histC[b], 1);
            atomicAdd(&histR[b2], 1);
        }
    }
    __syncthreads();

    // two 512-bin scans (all 8 waves each), separate wsum arrays, one barrier
    int v1 = histC[t];
    int inc1 = wave_incl_scan(v1, lane);
    if (lane == 63) wsumC[wid] = inc1;
    int v2 = histR[t];
    int inc2 = wave_incl_scan(v2, lane);
    if (lane == 63) wsumR[wid] = inc2;
    __syncthreads();
    int addC = 0, addR = 0;
    #pragma unroll
    for (int k = 0; k < 8; k++) {
        if (k < wid) { addC += wsumC[k]; addR += wsumR[k]; }
    }
    int exC = inc1 - v1 + addC;
    int exR = inc2 - v2 + addR;
    gbaseC[t] = (v1 > 0) ? (atomicAdd(&bcur[t], v1) - exC) : 0;
    gbaseR[t] = (v2 > 0) ? (atomicAdd(&bcurR[t], v2) - exR) : 0;
    histC[t] = exC;                // becomes cursor
    histR[t] = exR;
    __syncthreads();

    #pragma unroll
    for (int k = 0; k < NITP; k++) {
        int i = t + k * PT;
        if (i < cnt) {
            int p = atomicAdd(&histC[cb[k]], 1);
            stageC[p] = pk[k];
            bidC[p] = cb[k];
            int p2 = atomicAdd(&histR[rb[k]], 1);
            stageR[p2] = rpk[k];
            bidR[p2] = rb[k];
        }
    }
    __syncthreads();
    for (int p = t; p < cnt; p += PT) {
        int b = bidC[p];
        int idx = gbaseC[b] + p;
        if (idx < (b + 1) * CAP) part[idx] = stageC[p];      // overflow clamp
        int b2 = bidR[p];
        int idx2 = gbaseR[b2] + p;
        if (idx2 < (b2 + 1) * CAP) partR[idx2] = stageR[p];
    }
}

// per bucket: row counts -> dinv + xs = bf16(dinv*x)
__global__ __launch_bounds__(FT)
void k_fillR(const unsigned char* __restrict__ partR, const int* __restrict__ bcurR,
             const float4* __restrict__ x4, float* __restrict__ dinv,
             ushort4* __restrict__ xs4, int n) {
    __shared__ int lcnt[BCOLS];
    __shared__ float ldinv[BCOLS];
    int b = blockIdx.x;
    int s = b * CAP;
    int t = threadIdx.x;           // FT = 512

    int cntR = min(bcurR[b] - s, CAP);
    if (t < BCOLS) lcnt[t] = 0;
    __syncthreads();
    for (int i = t; i < cntR; i += FT)
        atomicAdd(&lcnt[partR[s + i]], 1);
    __syncthreads();
    if (t < BCOLS) {
        float d = rsqrtf((float)(lcnt[t] + 1));      // +1 self loop
        ldinv[t] = d;
        int gr = (b << BSHIFT) + t;
        if (gr < n) dinv[gr] = d;
    }
    __syncthreads();
    size_t base4 = (size_t)(b << BSHIFT) << 4;       // float4 index of row b*256
    int lim = min(BCOLS, n - (b << BSHIFT)) << 4;
    for (int i = t; i < lim; i += FT) {
        float dd = ldinv[i >> 4];
        float4 vv = x4[base4 + i];
        ushort4 o;
        o.x = f2bf(dd * vv.x); o.y = f2bf(dd * vv.y);
        o.z = f2bf(dd * vv.z); o.w = f2bf(dd * vv.w);
        xs4[base4 + i] = o;
    }
}

// per bucket: CSR in LDS, then register-accumulate gather, fused.
__global__ __launch_bounds__(UT)
void k_fuse(const int* __restrict__ part, const int* __restrict__ bcur,
            const unsigned short* __restrict__ xs,
            const float* __restrict__ dinv,
            float4* __restrict__ out4, int n) {
    __shared__ int lcnt[BCOLS];
    __shared__ int lps[BCOLS];
    __shared__ int cur[BCOLS];
    __shared__ int wsum[4];
    __shared__ int stage[CAP];
    int b = blockIdx.x;
    int s = b * CAP;
    int cnt = min(bcur[b] - s, CAP);
    int t = threadIdx.x;           // UT = 512
    int lane = t & 63, wid = t >> 6;

    // ---- phase C: count / scan / scatter row-ids into LDS stage ----
    if (t < BCOLS) lcnt[t] = 0;
    __syncthreads();

    int pk[FBIT];
    #pragma unroll
    for (int k = 0; k < FBIT; k++) {
        int i = t + k * UT;
        if (i < cnt) {
            int v2 = part[s + i];
            pk[k] = v2;
            atomicAdd(&lcnt[v2 >> 17], 1);
        }
    }
    __syncthreads();

    int v = 0, inc = 0;
    if (t < BCOLS) {
        v = lcnt[t];
        inc = wave_incl_scan(v, lane);
        if (lane == 63) wsum[wid] = inc;
    }
    __syncthreads();
    if (t < BCOLS) {
        int add = 0;
        if (wid > 0) add += wsum[0];
        if (wid > 1) add += wsum[1];
        if (wid > 2) add += wsum[2];
        int ex = inc - v + add;
        lps[t] = ex;
        cur[t] = ex;
    }
    __syncthreads();

    #pragma unroll
    for (int k = 0; k < FBIT; k++) {
        int i = t + k * UT;
        if (i < cnt) {
            int v2 = pk[k];
            int p = atomicAdd(&cur[v2 >> 17], 1);
            stage[p] = v2 & 0x1FFFF;     // pure row id
        }
    }
    __syncthreads();

    // ---- gather: 64 groups x 8 lanes; each group owns 4 cols ----
    int gg = t >> 3, li = t & 7;
    #pragma unroll
    for (int cc = 0; cc < BCOLS; cc += 64) {
        int c = cc + gg;
        int node = (b << BSHIFT) + c;
        if (node < n) {
            int ss = lps[c];
            int len = lcnt[c];
            float a0 = 0.f, a1 = 0.f, a2 = 0.f, a3 = 0.f;
            float a4 = 0.f, a5 = 0.f, a6 = 0.f, a7 = 0.f;
            int npair = len >> 1;
            uint4 u0, u1;
            if (npair > 0) {
                int r0 = stage[ss], r1 = stage[ss + 1];
                u0 = *((const uint4*)(xs + ((size_t)r0 << 6)) + li);
                u1 = *((const uint4*)(xs + ((size_t)r1 << 6)) + li);
            }
            for (int q = 1; q < npair; q++) {
                int p = ss + q * 2;
                int r0 = stage[p], r1 = stage[p + 1];
                uint4 n0 = *((const uint4*)(xs + ((size_t)r0 << 6)) + li);
                uint4 n1 = *((const uint4*)(xs + ((size_t)r1 << 6)) + li);
                a0 += bflo(u0.x); a1 += bfhi(u0.x);
                a2 += bflo(u0.y); a3 += bfhi(u0.y);
                a4 += bflo(u0.z); a5 += bfhi(u0.z);
                a6 += bflo(u0.w); a7 += bfhi(u0.w);
                a0 += bflo(u1.x); a1 += bfhi(u1.x);
                a2 += bflo(u1.y); a3 += bfhi(u1.y);
                a4 += bflo(u1.z); a5 += bfhi(u1.z);
                a6 += bflo(u1.w); a7 += bfhi(u1.w);
                u0 = n0; u1 = n1;
            }
            if (npair > 0) {
                a0 += bflo(u0.x); a1 += bfhi(u0.x);
                a2 += bflo(u0.y); a3 += bfhi(u0.y);
                a4 += bflo(u0.z); a5 += bfhi(u0.z);
                a6 += bflo(u0.w); a7 += bfhi(u0.w);
                a0 += bflo(u1.x); a1 += bfhi(u1.x);
                a2 += bflo(u1.y); a3 += bfhi(u1.y);
                a4 += bflo(u1.z); a5 += bfhi(u1.z);
                a6 += bflo(u1.w); a7 += bfhi(u1.w);
            }
            if (len & 1) {
                int r = stage[ss + len - 1];
                uint4 u = *((const uint4*)(xs + ((size_t)r << 6)) + li);
                a0 += bflo(u.x); a1 += bfhi(u.x);
                a2 += bflo(u.y); a3 += bfhi(u.y);
                a4 += bflo(u.z); a5 += bfhi(u.z);
                a6 += bflo(u.w); a7 += bfhi(u.w);
            }
            // self term + scale + store
            float dc = dinv[node];
            uint4 us = *((const uint4*)(xs + ((size_t)node << 6)) + li);
            float4 r0o, r1o;
            r0o.x = dc * (a0 + bflo(us.x));
            r0o.y = dc * (a1 + bfhi(us.x));
            r0o.z = dc * (a2 + bflo(us.y));
            r0o.w = dc * (a3 + bfhi(us.y));
            r1o.x = dc * (a4 + bflo(us.z));
            r1o.y = dc * (a5 + bfhi(us.z));
            r1o.z = dc * (a6 + bflo(us.w));
            r1o.w = dc * (a7 + bfhi(us.w));
            size_t ob = ((size_t)node << 4) + (li << 1);
            out4[ob] = r0o;
            out4[ob + 1] = r1o;
        }
    }
}

extern "C" void kernel_launch(void* const* d_in, const int* in_sizes, int n_in,
                              void* d_out, int out_size, void* d_ws, size_t ws_size,
                              hipStream_t stream) {
    const float* x    = (const float*)d_in[0];
    const int*   eidx = (const int*)d_in[1];   // int32 (JAX x64 disabled)

    const int n = in_sizes[0] / NFEAT;         // 100000
    const int E = in_sizes[1] / 2;             // 1600000
    const int* rows = eidx;
    const int* cols = eidx + E;
    float* out = (float*)d_out;

    const int nbuck = (n + BCOLS - 1) >> BSHIFT;   // 391

    // ws: bcur[NBMAX] | bcurR[NBMAX] | dinv[n]
    //     | xs[n*64 bf16, 16B-aligned] | part[nbuck*CAP ints] | partR[uchar]
    char* w = (char*)d_ws;
    int*   bcur  = (int*)w;     w += NBMAX * 4;
    int*   bcurR = (int*)w;     w += NBMAX * 4;
    float* dinv  = (float*)w;   w += (size_t)n * 4;
    w = (char*)(((uintptr_t)w + 15) & ~(uintptr_t)15);
    unsigned short* xs = (unsigned short*)w;  w += (size_t)n * NFEAT * 2;
    int*   part  = (int*)w;     w += (size_t)nbuck * CAP * 4;
    unsigned char* partR = (unsigned char*)w;

    k_init<<<1, NBMAX, 0, stream>>>(bcur, bcurR);

    int nchunk = (E + CHUNK - 1) / CHUNK;      // 391
    k_partCR<<<nchunk, PT, 0, stream>>>(rows, cols, bcur, bcurR, part, partR, E);
    k_fillR<<<nbuck, FT, 0, stream>>>(partR, bcurR, (const float4*)x,
                                      dinv, (ushort4*)xs, n);
    k_fuse<<<nbuck, UT, 0, stream>>>(part, bcur, xs, dinv,
                                     (float4*)out, n);
}